// Round 6
// baseline (396.976 us; speedup 1.0000x reference)
//
#include <hip/hip_runtime.h>

#define PXW 1920.0f
#define PXH 1080.0f
#define RELAXF 1.3f
#define NTHREADS 256
#define NBLOCKS 2048   // 8 blocks/CU x 256 CU (G11 memory-bound grid)

// Native clang vector type — required by __builtin_nontemporal_load/store
// (HIP's float4 is a class and is rejected by the builtin).
typedef float f4 __attribute__((ext_vector_type(4)));

// One group = 4 points, so every global access is an aligned 16B vector.
// All bulk traffic is nontemporal (read-once / write-once, zero reuse ->
// keep L2 out of the way). __launch_bounds__(256,4) allows 128 VGPRs so
// all 12 input loads stay in flight (MLP) instead of being serialized
// into a 32-VGPR budget.
__global__ __launch_bounds__(NTHREADS, 4) void cam_kernel(
    const float* __restrict__ pos3d,
    const float* __restrict__ cov3d,
    const float* __restrict__ view,
    const float* __restrict__ proj,
    float* __restrict__ out,   // [pos2d 3n | cov2d 4n | mask n]
    int n)
{
  // Uniform (wave-invariant) matrix loads -> scalar loads + broadcast.
  float V[12];
  float P[16];
#pragma unroll
  for (int i = 0; i < 12; ++i) V[i] = view[i];
#pragma unroll
  for (int i = 0; i < 16; ++i) P[i] = proj[i];

  const int ngroups = n >> 2;              // n % 4 == 0 (N = 4,000,000)
  const int stride  = NBLOCKS * NTHREADS;

  for (int g = blockIdx.x * blockDim.x + threadIdx.x; g < ngroups; g += stride) {
    // ---- load 4 points (12 x nontemporal 16B) ----
    const f4* p4 = reinterpret_cast<const f4*>(pos3d) + (size_t)3 * g;
    const f4 pa = __builtin_nontemporal_load(p4 + 0);
    const f4 pb = __builtin_nontemporal_load(p4 + 1);
    const f4 pc = __builtin_nontemporal_load(p4 + 2);

    const f4* c4 = reinterpret_cast<const f4*>(cov3d) + (size_t)9 * g;
    float cf[36];
#pragma unroll
    for (int i = 0; i < 9; ++i) {
      const f4 t = __builtin_nontemporal_load(c4 + i);
      cf[4 * i + 0] = t.x; cf[4 * i + 1] = t.y;
      cf[4 * i + 2] = t.z; cf[4 * i + 3] = t.w;
    }

    float px[4], py[4], pz[4];
    px[0] = pa.x; py[0] = pa.y; pz[0] = pa.z;
    px[1] = pa.w; py[1] = pb.x; pz[1] = pb.y;
    px[2] = pb.z; py[2] = pb.w; pz[2] = pc.x;
    px[3] = pc.y; py[3] = pc.z; pz[3] = pc.w;

    float o_pos[12];
    float o_cov[16];
    float o_msk[4];

#pragma unroll
    for (int k = 0; k < 4; ++k) {
      const float x = px[k], y = py[k], z = pz[k];

      // p_model = view[:3,:3] @ p + view[:3,3]   (row-major V)
      const float pm0 = V[0] * x + V[1] * y + V[2]  * z + V[3];
      const float pm1 = V[4] * x + V[5] * y + V[6]  * z + V[7];
      const float pm2 = V[8] * x + V[9] * y + V[10] * z + V[11];

      // clip = P @ [pm, 1]
      const float c0 = P[0]  * pm0 + P[1]  * pm1 + P[2]  * pm2 + P[3];
      const float c1 = P[4]  * pm0 + P[5]  * pm1 + P[6]  * pm2 + P[7];
      const float c2 = P[8]  * pm0 + P[9]  * pm1 + P[10] * pm2 + P[11];
      const float c3 = P[12] * pm0 + P[13] * pm1 + P[14] * pm2 + P[15];

      const float iw = 1.0f / (c3 + 1e-6f);
      const float nx = c0 * iw, ny = c1 * iw, nz = c2 * iw;

      const bool m = (nz >= 0.2f) && (nx >= -RELAXF) && (nx <= RELAXF)
                                  && (ny >= -RELAXF) && (ny <= RELAXF);

      const float sx = 0.5f * (nx + 1.0f) * PXW;
      const float sy = (1.0f - 0.5f * (ny + 1.0f)) * PXH;

      o_pos[3 * k + 0] = m ? sx : 0.0f;
      o_pos[3 * k + 1] = m ? sy : 0.0f;
      o_pos[3 * k + 2] = m ? nz : 0.0f;
      o_msk[k]         = m ? 1.0f : 0.0f;

      // JW = J @ Wm, Wm = view[:3,:3]^T  =>  Wm[r][c] = V[4c + r]
      const float iz = 1.0f / z;
      const float a0 = iz * (V[0] - x * V[2]);
      const float a1 = iz * (V[4] - x * V[6]);
      const float a2 = iz * (V[8] - x * V[10]);
      const float b0 = iz * (V[1] - y * V[2]);
      const float b1 = iz * (V[5] - y * V[6]);
      const float b2 = iz * (V[9] - y * V[10]);

      const float* C = &cf[9 * k];
      const float u0 = C[0] * a0 + C[1] * a1 + C[2] * a2;
      const float u1 = C[3] * a0 + C[4] * a1 + C[5] * a2;
      const float u2 = C[6] * a0 + C[7] * a1 + C[8] * a2;
      const float v0 = C[0] * b0 + C[1] * b1 + C[2] * b2;
      const float v1 = C[3] * b0 + C[4] * b1 + C[5] * b2;
      const float v2 = C[6] * b0 + C[7] * b1 + C[8] * b2;

      const float c00 = a0 * u0 + a1 * u1 + a2 * u2;
      const float c01 = a0 * v0 + a1 * v1 + a2 * v2;
      const float c10 = b0 * u0 + b1 * u1 + b2 * u2;
      const float c11 = b0 * v0 + b1 * v1 + b2 * v2;

      o_cov[4 * k + 0] = m ? c00 : 0.0f;
      o_cov[4 * k + 1] = m ? c01 : 0.0f;
      o_cov[4 * k + 2] = m ? c10 : 0.0f;
      o_cov[4 * k + 3] = m ? c11 : 0.0f;
    }

    // ---- store (8 x nontemporal 16B) ----
    f4* op = reinterpret_cast<f4*>(out) + (size_t)3 * g;
    f4 t0 = { o_pos[0], o_pos[1], o_pos[2],  o_pos[3]  };
    f4 t1 = { o_pos[4], o_pos[5], o_pos[6],  o_pos[7]  };
    f4 t2 = { o_pos[8], o_pos[9], o_pos[10], o_pos[11] };
    __builtin_nontemporal_store(t0, op + 0);
    __builtin_nontemporal_store(t1, op + 1);
    __builtin_nontemporal_store(t2, op + 2);

    f4* oc = reinterpret_cast<f4*>(out + (size_t)3 * n) + (size_t)4 * g;
#pragma unroll
    for (int k = 0; k < 4; ++k) {
      f4 tc = { o_cov[4 * k + 0], o_cov[4 * k + 1],
                o_cov[4 * k + 2], o_cov[4 * k + 3] };
      __builtin_nontemporal_store(tc, oc + k);
    }

    f4 tm = { o_msk[0], o_msk[1], o_msk[2], o_msk[3] };
    __builtin_nontemporal_store(tm, reinterpret_cast<f4*>(out + (size_t)7 * n) + g);
  }
}

extern "C" void kernel_launch(void* const* d_in, const int* in_sizes, int n_in,
                              void* d_out, int out_size, void* d_ws, size_t ws_size,
                              hipStream_t stream) {
  const float* pos3d = (const float*)d_in[0];
  const float* cov3d = (const float*)d_in[1];
  const float* view  = (const float*)d_in[2];
  const float* proj  = (const float*)d_in[3];

  const int n = in_sizes[0] / 3;            // 4,000,000

  cam_kernel<<<NBLOCKS, NTHREADS, 0, stream>>>(pos3d, cov3d, view, proj,
                                               (float*)d_out, n);
}

// Round 8
// 278.763 us; speedup vs baseline: 1.4241x; 1.4241x over previous
//
#include <hip/hip_runtime.h>

#define PXW 1920.0f
#define PXH 1080.0f
#define RELAXF 1.3f

#define NT 256
#define TILE_PTS 1024
#define POS_F4 768      // 1024 pts * 3 floats / 4
#define COV_F4 2304     // 1024 pts * 9 floats / 4
// out staging reuses sCov: opos f4 [0,768) + ocov f4 [768,1792) <= 2304

typedef float f4 __attribute__((ext_vector_type(4)));

// XOR involution on f4-slot index: spreads stride-9 (and stride-4) record
// reads across banks while keeping each 8-slot (128B) group closed, so the
// coalesced write side stays conflict-free. Applied to BOTH writes and reads
// of the sCov buffer (rule: both-sides-or-neither).
__device__ __forceinline__ int swz(int s) { return s ^ ((s >> 3) & 7); }

__global__ __launch_bounds__(NT, 3) void cam_kernel(
    const float* __restrict__ pos3d,
    const float* __restrict__ cov3d,
    const float* __restrict__ view,
    const float* __restrict__ proj,
    float* __restrict__ out,   // [pos2d 3n | cov2d 4n | mask n]
    int n)
{
  __shared__ f4 sPos[POS_F4];
  __shared__ f4 sCov[COV_F4];

  const int b = blockIdx.x;
  const int t = threadIdx.x;
  const long long p0 = (long long)b * TILE_PTS;

  float V[12];
  float P[16];
#pragma unroll
  for (int i = 0; i < 12; ++i) V[i] = view[i];
#pragma unroll
  for (int i = 0; i < 16; ++i) P[i] = proj[i];

  if (p0 + TILE_PTS <= n) {
    // ================= fast path: full tile, LDS-staged =================
    // ---- stage in: perfectly coalesced f4 loads -> LDS ----
    const f4* gp = reinterpret_cast<const f4*>(pos3d) + (size_t)POS_F4 * b;
    const f4* gc = reinterpret_cast<const f4*>(cov3d) + (size_t)COV_F4 * b;
    f4 rp[3], rc[9];
#pragma unroll
    for (int j = 0; j < 3; ++j) rp[j] = gp[t + NT * j];
#pragma unroll
    for (int j = 0; j < 9; ++j) rc[j] = gc[t + NT * j];
#pragma unroll
    for (int j = 0; j < 3; ++j) sPos[t + NT * j] = rp[j];
#pragma unroll
    for (int j = 0; j < 9; ++j) sCov[swz(t + NT * j)] = rc[j];
    __syncthreads();

    // ---- read my 4 points from LDS ----
    const f4 pa = sPos[3 * t + 0];
    const f4 pb = sPos[3 * t + 1];
    const f4 pc = sPos[3 * t + 2];
    float cf[36];
#pragma unroll
    for (int j = 0; j < 9; ++j) {
      const f4 c = sCov[swz(9 * t + j)];
      cf[4 * j + 0] = c.x; cf[4 * j + 1] = c.y;
      cf[4 * j + 2] = c.z; cf[4 * j + 3] = c.w;
    }

    float px[4], py[4], pz[4];
    px[0] = pa.x; py[0] = pa.y; pz[0] = pa.z;
    px[1] = pa.w; py[1] = pb.x; pz[1] = pb.y;
    px[2] = pb.z; py[2] = pb.w; pz[2] = pc.x;
    px[3] = pc.y; py[3] = pc.z; pz[3] = pc.w;

    float o_pos[12], o_cov[16], o_msk[4];

#pragma unroll
    for (int k = 0; k < 4; ++k) {
      const float x = px[k], y = py[k], z = pz[k];

      const float pm0 = V[0] * x + V[1] * y + V[2]  * z + V[3];
      const float pm1 = V[4] * x + V[5] * y + V[6]  * z + V[7];
      const float pm2 = V[8] * x + V[9] * y + V[10] * z + V[11];

      const float c0 = P[0]  * pm0 + P[1]  * pm1 + P[2]  * pm2 + P[3];
      const float c1 = P[4]  * pm0 + P[5]  * pm1 + P[6]  * pm2 + P[7];
      const float c2 = P[8]  * pm0 + P[9]  * pm1 + P[10] * pm2 + P[11];
      const float c3 = P[12] * pm0 + P[13] * pm1 + P[14] * pm2 + P[15];

      const float iw = 1.0f / (c3 + 1e-6f);
      const float nx = c0 * iw, ny = c1 * iw, nz = c2 * iw;

      const bool m = (nz >= 0.2f) && (nx >= -RELAXF) && (nx <= RELAXF)
                                  && (ny >= -RELAXF) && (ny <= RELAXF);

      const float sx = 0.5f * (nx + 1.0f) * PXW;
      const float sy = (1.0f - 0.5f * (ny + 1.0f)) * PXH;

      o_pos[3 * k + 0] = m ? sx : 0.0f;
      o_pos[3 * k + 1] = m ? sy : 0.0f;
      o_pos[3 * k + 2] = m ? nz : 0.0f;
      o_msk[k]         = m ? 1.0f : 0.0f;

      const float iz = 1.0f / z;
      const float a0 = iz * (V[0] - x * V[2]);
      const float a1 = iz * (V[4] - x * V[6]);
      const float a2 = iz * (V[8] - x * V[10]);
      const float b0 = iz * (V[1] - y * V[2]);
      const float b1 = iz * (V[5] - y * V[6]);
      const float b2 = iz * (V[9] - y * V[10]);

      const float* C = &cf[9 * k];
      const float u0 = C[0] * a0 + C[1] * a1 + C[2] * a2;
      const float u1 = C[3] * a0 + C[4] * a1 + C[5] * a2;
      const float u2 = C[6] * a0 + C[7] * a1 + C[8] * a2;
      const float v0 = C[0] * b0 + C[1] * b1 + C[2] * b2;
      const float v1 = C[3] * b0 + C[4] * b1 + C[5] * b2;
      const float v2 = C[6] * b0 + C[7] * b1 + C[8] * b2;

      o_cov[4 * k + 0] = m ? (a0 * u0 + a1 * u1 + a2 * u2) : 0.0f;
      o_cov[4 * k + 1] = m ? (a0 * v0 + a1 * v1 + a2 * v2) : 0.0f;
      o_cov[4 * k + 2] = m ? (b0 * u0 + b1 * u1 + b2 * u2) : 0.0f;
      o_cov[4 * k + 3] = m ? (b0 * v0 + b1 * v1 + b2 * v2) : 0.0f;
    }

    // mask is naturally 1 f4/thread -> direct coalesced store (no staging)
    f4 tm = { o_msk[0], o_msk[1], o_msk[2], o_msk[3] };
    reinterpret_cast<f4*>(out + (size_t)7 * n)[(size_t)NT * b + t] = tm;

    // ---- stage out through LDS (reuse sCov after all reads done) ----
    __syncthreads();
#pragma unroll
    for (int c = 0; c < 3; ++c) {
      f4 v = { o_pos[4 * c + 0], o_pos[4 * c + 1],
               o_pos[4 * c + 2], o_pos[4 * c + 3] };
      sCov[swz(3 * t + c)] = v;
    }
#pragma unroll
    for (int c = 0; c < 4; ++c) {
      f4 v = { o_cov[4 * c + 0], o_cov[4 * c + 1],
               o_cov[4 * c + 2], o_cov[4 * c + 3] };
      sCov[swz(POS_F4 + 4 * t + c)] = v;
    }
    __syncthreads();

    // ---- coalesced stores ----
    f4* opg = reinterpret_cast<f4*>(out) + (size_t)POS_F4 * b;
#pragma unroll
    for (int j = 0; j < 3; ++j) opg[t + NT * j] = sCov[swz(t + NT * j)];

    f4* ocg = reinterpret_cast<f4*>(out + (size_t)3 * n) + (size_t)1024 * b;
#pragma unroll
    for (int j = 0; j < 4; ++j)
      ocg[t + NT * j] = sCov[swz(POS_F4 + t + NT * j)];

  } else {
    // ================= tail path (last partial tile) =================
    for (long long g = p0 / 4 + t; 4 * g < n; g += NT) {
      const float4* p4 = reinterpret_cast<const float4*>(pos3d) + (size_t)3 * g;
      const float4 pa = p4[0], pb = p4[1], pc = p4[2];
      float px[4], py[4], pz[4];
      px[0] = pa.x; py[0] = pa.y; pz[0] = pa.z;
      px[1] = pa.w; py[1] = pb.x; pz[1] = pb.y;
      px[2] = pb.z; py[2] = pb.w; pz[2] = pc.x;
      px[3] = pc.y; py[3] = pc.z; pz[3] = pc.w;

      const float4* c4 = reinterpret_cast<const float4*>(cov3d) + (size_t)9 * g;
      float cf[36];
#pragma unroll
      for (int i = 0; i < 9; ++i) {
        const float4 tt = c4[i];
        cf[4 * i + 0] = tt.x; cf[4 * i + 1] = tt.y;
        cf[4 * i + 2] = tt.z; cf[4 * i + 3] = tt.w;
      }

      float o_pos[12], o_cov[16], o_msk[4];
#pragma unroll
      for (int k = 0; k < 4; ++k) {
        const float x = px[k], y = py[k], z = pz[k];
        const float pm0 = V[0] * x + V[1] * y + V[2]  * z + V[3];
        const float pm1 = V[4] * x + V[5] * y + V[6]  * z + V[7];
        const float pm2 = V[8] * x + V[9] * y + V[10] * z + V[11];
        const float c0 = P[0]  * pm0 + P[1]  * pm1 + P[2]  * pm2 + P[3];
        const float c1 = P[4]  * pm0 + P[5]  * pm1 + P[6]  * pm2 + P[7];
        const float c2 = P[8]  * pm0 + P[9]  * pm1 + P[10] * pm2 + P[11];
        const float c3 = P[12] * pm0 + P[13] * pm1 + P[14] * pm2 + P[15];
        const float iw = 1.0f / (c3 + 1e-6f);
        const float nx = c0 * iw, ny = c1 * iw, nz = c2 * iw;
        const bool m = (nz >= 0.2f) && (nx >= -RELAXF) && (nx <= RELAXF)
                                    && (ny >= -RELAXF) && (ny <= RELAXF);
        const float sx = 0.5f * (nx + 1.0f) * PXW;
        const float sy = (1.0f - 0.5f * (ny + 1.0f)) * PXH;
        o_pos[3 * k + 0] = m ? sx : 0.0f;
        o_pos[3 * k + 1] = m ? sy : 0.0f;
        o_pos[3 * k + 2] = m ? nz : 0.0f;
        o_msk[k]         = m ? 1.0f : 0.0f;
        const float iz = 1.0f / z;
        const float a0 = iz * (V[0] - x * V[2]);
        const float a1 = iz * (V[4] - x * V[6]);
        const float a2 = iz * (V[8] - x * V[10]);
        const float b0 = iz * (V[1] - y * V[2]);
        const float b1 = iz * (V[5] - y * V[6]);
        const float b2 = iz * (V[9] - y * V[10]);
        const float* C = &cf[9 * k];
        const float u0 = C[0] * a0 + C[1] * a1 + C[2] * a2;
        const float u1 = C[3] * a0 + C[4] * a1 + C[5] * a2;
        const float u2 = C[6] * a0 + C[7] * a1 + C[8] * a2;
        const float v0 = C[0] * b0 + C[1] * b1 + C[2] * b2;
        const float v1 = C[3] * b0 + C[4] * b1 + C[5] * b2;
        const float v2 = C[6] * b0 + C[7] * b1 + C[8] * b2;
        o_cov[4 * k + 0] = m ? (a0 * u0 + a1 * u1 + a2 * u2) : 0.0f;
        o_cov[4 * k + 1] = m ? (a0 * v0 + a1 * v1 + a2 * v2) : 0.0f;
        o_cov[4 * k + 2] = m ? (b0 * u0 + b1 * u1 + b2 * u2) : 0.0f;
        o_cov[4 * k + 3] = m ? (b0 * v0 + b1 * v1 + b2 * v2) : 0.0f;
      }

      float4* op = reinterpret_cast<float4*>(out) + (size_t)3 * g;
      op[0] = make_float4(o_pos[0], o_pos[1], o_pos[2],  o_pos[3]);
      op[1] = make_float4(o_pos[4], o_pos[5], o_pos[6],  o_pos[7]);
      op[2] = make_float4(o_pos[8], o_pos[9], o_pos[10], o_pos[11]);
      float4* oc = reinterpret_cast<float4*>(out + (size_t)3 * n) + (size_t)4 * g;
#pragma unroll
      for (int k = 0; k < 4; ++k)
        oc[k] = make_float4(o_cov[4 * k + 0], o_cov[4 * k + 1],
                            o_cov[4 * k + 2], o_cov[4 * k + 3]);
      reinterpret_cast<float4*>(out + (size_t)7 * n)[g] =
          make_float4(o_msk[0], o_msk[1], o_msk[2], o_msk[3]);
    }
  }
}

extern "C" void kernel_launch(void* const* d_in, const int* in_sizes, int n_in,
                              void* d_out, int out_size, void* d_ws, size_t ws_size,
                              hipStream_t stream) {
  const float* pos3d = (const float*)d_in[0];
  const float* cov3d = (const float*)d_in[1];
  const float* view  = (const float*)d_in[2];
  const float* proj  = (const float*)d_in[3];

  const int n = in_sizes[0] / 3;            // 4,000,000

  const int blocks = (n + TILE_PTS - 1) / TILE_PTS;   // 3907
  cam_kernel<<<blocks, NT, 0, stream>>>(pos3d, cov3d, view, proj,
                                        (float*)d_out, n);
}

// Round 9
// 278.604 us; speedup vs baseline: 1.4249x; 1.0006x over previous
//
#include <hip/hip_runtime.h>

#define PXW 1920.0f
#define PXH 1080.0f
#define RELAXF 1.3f
#define NT 256          // 4 waves per block

typedef float f4 __attribute__((ext_vector_type(4)));

// Per-wave LDS slice: 576 f4 = 9 KB.
//   stage-in : cov tile, slots [0,576), linear (stride-9 reads are odd -> bank-optimal)
//   stage-out: opos slots [0,192) stride-3 (odd), ocov slots [192,512) stride-5 (odd, padded)
// All staging is WAVE-PRIVATE: no __syncthreads anywhere; wave-internal
// lgkmcnt ordering (compiler-inserted) is sufficient, waves run decoupled.
#define WSLICE 576

__global__ __launch_bounds__(NT, 4) void cam_kernel(
    const float* __restrict__ pos3d,
    const float* __restrict__ cov3d,
    const float* __restrict__ view,
    const float* __restrict__ proj,
    float* __restrict__ out,   // [pos2d 3n | cov2d 4n | mask n]
    int n)
{
  __shared__ f4 sBuf[4 * WSLICE];   // 36 KB -> 4 blocks/CU

  const int l   = threadIdx.x & 63;
  const int w   = threadIdx.x >> 6;
  const int wt  = blockIdx.x * 4 + w;    // wave-tile id (256 points each)
  const int nwt = n >> 8;                // full wave tiles (15625 for N=4e6)
  f4* S = sBuf + w * WSLICE;

  float V[12], P[16];
#pragma unroll
  for (int i = 0; i < 12; ++i) V[i] = view[i];
#pragma unroll
  for (int i = 0; i < 16; ++i) P[i] = proj[i];

  if (wt < nwt) {
    // ---- issue all global loads first (12 in flight) ----
    const f4* gc = reinterpret_cast<const f4*>(cov3d) + (size_t)576 * wt;
    f4 rc[9];
#pragma unroll
    for (int j = 0; j < 9; ++j) rc[j] = gc[l + 64 * j];

    const f4* gp = reinterpret_cast<const f4*>(pos3d) + (size_t)192 * wt + 3 * l;
    const f4 pa = gp[0], pb = gp[1], pc = gp[2];   // record-strided, cache-filled

    // ---- cov transpose through wave-private LDS (coalesced write, stride-9 read) ----
#pragma unroll
    for (int j = 0; j < 9; ++j) S[l + 64 * j] = rc[j];

    float cf[36];
#pragma unroll
    for (int j = 0; j < 9; ++j) {
      const f4 c = S[9 * l + j];
      cf[4 * j + 0] = c.x; cf[4 * j + 1] = c.y;
      cf[4 * j + 2] = c.z; cf[4 * j + 3] = c.w;
    }

    float px[4], py[4], pz[4];
    px[0] = pa.x; py[0] = pa.y; pz[0] = pa.z;
    px[1] = pa.w; py[1] = pb.x; pz[1] = pb.y;
    px[2] = pb.z; py[2] = pb.w; pz[2] = pc.x;
    px[3] = pc.y; py[3] = pc.z; pz[3] = pc.w;

    float o_pos[12], o_cov[16], o_msk[4];

#pragma unroll
    for (int k = 0; k < 4; ++k) {
      const float x = px[k], y = py[k], z = pz[k];

      const float pm0 = V[0] * x + V[1] * y + V[2]  * z + V[3];
      const float pm1 = V[4] * x + V[5] * y + V[6]  * z + V[7];
      const float pm2 = V[8] * x + V[9] * y + V[10] * z + V[11];

      const float c0 = P[0]  * pm0 + P[1]  * pm1 + P[2]  * pm2 + P[3];
      const float c1 = P[4]  * pm0 + P[5]  * pm1 + P[6]  * pm2 + P[7];
      const float c2 = P[8]  * pm0 + P[9]  * pm1 + P[10] * pm2 + P[11];
      const float c3 = P[12] * pm0 + P[13] * pm1 + P[14] * pm2 + P[15];

      const float iw = 1.0f / (c3 + 1e-6f);
      const float nx = c0 * iw, ny = c1 * iw, nz = c2 * iw;

      const bool m = (nz >= 0.2f) && (nx >= -RELAXF) && (nx <= RELAXF)
                                  && (ny >= -RELAXF) && (ny <= RELAXF);

      const float sx = 0.5f * (nx + 1.0f) * PXW;
      const float sy = (1.0f - 0.5f * (ny + 1.0f)) * PXH;

      o_pos[3 * k + 0] = m ? sx : 0.0f;
      o_pos[3 * k + 1] = m ? sy : 0.0f;
      o_pos[3 * k + 2] = m ? nz : 0.0f;
      o_msk[k]         = m ? 1.0f : 0.0f;

      const float iz = 1.0f / z;
      const float a0 = iz * (V[0] - x * V[2]);
      const float a1 = iz * (V[4] - x * V[6]);
      const float a2 = iz * (V[8] - x * V[10]);
      const float b0 = iz * (V[1] - y * V[2]);
      const float b1 = iz * (V[5] - y * V[6]);
      const float b2 = iz * (V[9] - y * V[10]);

      const float* C = &cf[9 * k];
      const float u0 = C[0] * a0 + C[1] * a1 + C[2] * a2;
      const float u1 = C[3] * a0 + C[4] * a1 + C[5] * a2;
      const float u2 = C[6] * a0 + C[7] * a1 + C[8] * a2;
      const float v0 = C[0] * b0 + C[1] * b1 + C[2] * b2;
      const float v1 = C[3] * b0 + C[4] * b1 + C[5] * b2;
      const float v2 = C[6] * b0 + C[7] * b1 + C[8] * b2;

      o_cov[4 * k + 0] = m ? (a0 * u0 + a1 * u1 + a2 * u2) : 0.0f;
      o_cov[4 * k + 1] = m ? (a0 * v0 + a1 * v1 + a2 * v2) : 0.0f;
      o_cov[4 * k + 2] = m ? (b0 * u0 + b1 * u1 + b2 * u2) : 0.0f;
      o_cov[4 * k + 3] = m ? (b0 * v0 + b1 * v1 + b2 * v2) : 0.0f;
    }

    // ---- mask: naturally coalesced, direct store ----
    f4 tm = { o_msk[0], o_msk[1], o_msk[2], o_msk[3] };
    reinterpret_cast<f4*>(out + (size_t)7 * n)[(size_t)64 * wt + l] = tm;

    // ---- stage outputs in the same slice (WAR on LDS, lgkmcnt-ordered) ----
#pragma unroll
    for (int c = 0; c < 3; ++c) {
      f4 v = { o_pos[4 * c + 0], o_pos[4 * c + 1],
               o_pos[4 * c + 2], o_pos[4 * c + 3] };
      S[3 * l + c] = v;                       // stride-3 (odd): bank-optimal
    }
#pragma unroll
    for (int c = 0; c < 4; ++c) {
      f4 v = { o_cov[4 * c + 0], o_cov[4 * c + 1],
               o_cov[4 * c + 2], o_cov[4 * c + 3] };
      S[192 + 5 * l + c] = v;                 // stride-5 (odd, padded from 4)
    }

    // ---- coalesced stores ----
    f4* gop = reinterpret_cast<f4*>(out) + (size_t)192 * wt;
#pragma unroll
    for (int j = 0; j < 3; ++j) gop[l + 64 * j] = S[l + 64 * j];

    f4* goc = reinterpret_cast<f4*>(out + (size_t)3 * n) + (size_t)256 * wt;
#pragma unroll
    for (int j = 0; j < 4; ++j) {
      const int i = l + 64 * j;
      goc[i] = S[192 + 5 * (i >> 2) + (i & 3)];
    }

  } else if (wt == nwt) {
    // ---- tail: leftover 4-point groups (empty when n % 256 == 0) ----
    for (int g = nwt * 64 + l; g < (n >> 2); g += 64) {
      const float4* p4 = reinterpret_cast<const float4*>(pos3d) + (size_t)3 * g;
      const float4 ta = p4[0], tb = p4[1], tc = p4[2];
      float px[4], py[4], pz[4];
      px[0] = ta.x; py[0] = ta.y; pz[0] = ta.z;
      px[1] = ta.w; py[1] = tb.x; pz[1] = tb.y;
      px[2] = tb.z; py[2] = tb.w; pz[2] = tc.x;
      px[3] = tc.y; py[3] = tc.z; pz[3] = tc.w;

      const float4* c4 = reinterpret_cast<const float4*>(cov3d) + (size_t)9 * g;
      float cf[36];
#pragma unroll
      for (int i = 0; i < 9; ++i) {
        const float4 tt = c4[i];
        cf[4 * i + 0] = tt.x; cf[4 * i + 1] = tt.y;
        cf[4 * i + 2] = tt.z; cf[4 * i + 3] = tt.w;
      }

      float o_pos[12], o_cov[16], o_msk[4];
#pragma unroll
      for (int k = 0; k < 4; ++k) {
        const float x = px[k], y = py[k], z = pz[k];
        const float pm0 = V[0] * x + V[1] * y + V[2]  * z + V[3];
        const float pm1 = V[4] * x + V[5] * y + V[6]  * z + V[7];
        const float pm2 = V[8] * x + V[9] * y + V[10] * z + V[11];
        const float c0 = P[0]  * pm0 + P[1]  * pm1 + P[2]  * pm2 + P[3];
        const float c1 = P[4]  * pm0 + P[5]  * pm1 + P[6]  * pm2 + P[7];
        const float c2 = P[8]  * pm0 + P[9]  * pm1 + P[10] * pm2 + P[11];
        const float c3 = P[12] * pm0 + P[13] * pm1 + P[14] * pm2 + P[15];
        const float iw = 1.0f / (c3 + 1e-6f);
        const float nx = c0 * iw, ny = c1 * iw, nz = c2 * iw;
        const bool m = (nz >= 0.2f) && (nx >= -RELAXF) && (nx <= RELAXF)
                                    && (ny >= -RELAXF) && (ny <= RELAXF);
        const float sx = 0.5f * (nx + 1.0f) * PXW;
        const float sy = (1.0f - 0.5f * (ny + 1.0f)) * PXH;
        o_pos[3 * k + 0] = m ? sx : 0.0f;
        o_pos[3 * k + 1] = m ? sy : 0.0f;
        o_pos[3 * k + 2] = m ? nz : 0.0f;
        o_msk[k]         = m ? 1.0f : 0.0f;
        const float iz = 1.0f / z;
        const float a0 = iz * (V[0] - x * V[2]);
        const float a1 = iz * (V[4] - x * V[6]);
        const float a2 = iz * (V[8] - x * V[10]);
        const float b0 = iz * (V[1] - y * V[2]);
        const float b1 = iz * (V[5] - y * V[6]);
        const float b2 = iz * (V[9] - y * V[10]);
        const float* C = &cf[9 * k];
        const float u0 = C[0] * a0 + C[1] * a1 + C[2] * a2;
        const float u1 = C[3] * a0 + C[4] * a1 + C[5] * a2;
        const float u2 = C[6] * a0 + C[7] * a1 + C[8] * a2;
        const float v0 = C[0] * b0 + C[1] * b1 + C[2] * b2;
        const float v1 = C[3] * b0 + C[4] * b1 + C[5] * b2;
        const float v2 = C[6] * b0 + C[7] * b1 + C[8] * b2;
        o_cov[4 * k + 0] = m ? (a0 * u0 + a1 * u1 + a2 * u2) : 0.0f;
        o_cov[4 * k + 1] = m ? (a0 * v0 + a1 * v1 + a2 * v2) : 0.0f;
        o_cov[4 * k + 2] = m ? (b0 * u0 + b1 * u1 + b2 * u2) : 0.0f;
        o_cov[4 * k + 3] = m ? (b0 * v0 + b1 * v1 + b2 * v2) : 0.0f;
      }

      float4* op = reinterpret_cast<float4*>(out) + (size_t)3 * g;
      op[0] = make_float4(o_pos[0], o_pos[1], o_pos[2],  o_pos[3]);
      op[1] = make_float4(o_pos[4], o_pos[5], o_pos[6],  o_pos[7]);
      op[2] = make_float4(o_pos[8], o_pos[9], o_pos[10], o_pos[11]);
      float4* oc = reinterpret_cast<float4*>(out + (size_t)3 * n) + (size_t)4 * g;
#pragma unroll
      for (int k = 0; k < 4; ++k)
        oc[k] = make_float4(o_cov[4 * k + 0], o_cov[4 * k + 1],
                            o_cov[4 * k + 2], o_cov[4 * k + 3]);
      reinterpret_cast<float4*>(out + (size_t)7 * n)[g] =
          make_float4(o_msk[0], o_msk[1], o_msk[2], o_msk[3]);
    }
  }
}

extern "C" void kernel_launch(void* const* d_in, const int* in_sizes, int n_in,
                              void* d_out, int out_size, void* d_ws, size_t ws_size,
                              hipStream_t stream) {
  const float* pos3d = (const float*)d_in[0];
  const float* cov3d = (const float*)d_in[1];
  const float* view  = (const float*)d_in[2];
  const float* proj  = (const float*)d_in[3];

  const int n = in_sizes[0] / 3;            // 4,000,000

  const int groups = n >> 2;                             // 1,000,000
  const int blocks = (groups + 4 * 64 - 1) / (4 * 64);   // 3907
  cam_kernel<<<blocks, NT, 0, stream>>>(pos3d, cov3d, view, proj,
                                        (float*)d_out, n);
}

// Round 10
// 277.341 us; speedup vs baseline: 1.4314x; 1.0046x over previous
//
#include <hip/hip_runtime.h>

#define PXW 1920.0f
#define PXH 1080.0f
#define RELAXF 1.3f
#define NT 256          // 4 waves per block

typedef float f4 __attribute__((ext_vector_type(4)));

#define AS1 __attribute__((address_space(1)))
#define AS3 __attribute__((address_space(3)))

// Per-wave LDS slice: 576 f4 = 9 KB (wave-private -> NO __syncthreads).
//   stage-in : cov tile slots [0,576) filled by global_load_lds DMA
//              (dest = wave-uniform base + lane*16B, LDS linear as required)
//   stage-out: opos slots [0,192) stride-3 (odd), ocov [192,512) stride-5 (odd)
#define WSLICE 576

__global__ __launch_bounds__(NT, 4) void cam_kernel(
    const float* __restrict__ pos3d,
    const float* __restrict__ cov3d,
    const float* __restrict__ view,
    const float* __restrict__ proj,
    float* __restrict__ out,   // [pos2d 3n | cov2d 4n | mask n]
    int n)
{
  __shared__ f4 sBuf[4 * WSLICE];   // 36 KB -> 4 blocks/CU

  const int l   = threadIdx.x & 63;
  const int w   = threadIdx.x >> 6;
  const int wt  = blockIdx.x * 4 + w;    // wave-tile id (256 points each)
  const int nwt = n >> 8;                // full wave tiles (15625 for N=4e6)
  f4* S = sBuf + w * WSLICE;

  float V[12], P[16];
#pragma unroll
  for (int i = 0; i < 12; ++i) V[i] = view[i];
#pragma unroll
  for (int i = 0; i < 16; ++i) P[i] = proj[i];

  if (wt < nwt) {
    // ---- cov staging: 9 LDS-DMAs, no VGPR destinations, all in flight ----
    const f4* gc = reinterpret_cast<const f4*>(cov3d) + (size_t)576 * wt;
#pragma unroll
    for (int j = 0; j < 9; ++j) {
      __builtin_amdgcn_global_load_lds(
          (AS1 const void*)(gc + 64 * j + l),   // per-lane global src
          (AS3 void*)(S + 64 * j),              // wave-uniform LDS base (+16B*lane by HW)
          16, 0, 0);
    }

    // pos: 3 f4 loads per thread (record-strided; sibling instrs hit L1)
    const f4* gp = reinterpret_cast<const f4*>(pos3d) + (size_t)192 * wt + 3 * l;
    const f4 pa = gp[0], pb = gp[1], pc = gp[2];

    // Drain DMAs (and pos loads) before touching S.
    asm volatile("s_waitcnt vmcnt(0)" ::: "memory");
    __builtin_amdgcn_sched_barrier(0);

    float cf[36];
#pragma unroll
    for (int j = 0; j < 9; ++j) {
      const f4 c = S[9 * l + j];       // stride-9 (odd) -> near-conflict-free
      cf[4 * j + 0] = c.x; cf[4 * j + 1] = c.y;
      cf[4 * j + 2] = c.z; cf[4 * j + 3] = c.w;
    }

    float px[4], py[4], pz[4];
    px[0] = pa.x; py[0] = pa.y; pz[0] = pa.z;
    px[1] = pa.w; py[1] = pb.x; pz[1] = pb.y;
    px[2] = pb.z; py[2] = pb.w; pz[2] = pc.x;
    px[3] = pc.y; py[3] = pc.z; pz[3] = pc.w;

    float o_pos[12], o_cov[16], o_msk[4];

#pragma unroll
    for (int k = 0; k < 4; ++k) {
      const float x = px[k], y = py[k], z = pz[k];

      const float pm0 = V[0] * x + V[1] * y + V[2]  * z + V[3];
      const float pm1 = V[4] * x + V[5] * y + V[6]  * z + V[7];
      const float pm2 = V[8] * x + V[9] * y + V[10] * z + V[11];

      const float c0 = P[0]  * pm0 + P[1]  * pm1 + P[2]  * pm2 + P[3];
      const float c1 = P[4]  * pm0 + P[5]  * pm1 + P[6]  * pm2 + P[7];
      const float c2 = P[8]  * pm0 + P[9]  * pm1 + P[10] * pm2 + P[11];
      const float c3 = P[12] * pm0 + P[13] * pm1 + P[14] * pm2 + P[15];

      const float iw = 1.0f / (c3 + 1e-6f);
      const float nx = c0 * iw, ny = c1 * iw, nz = c2 * iw;

      const bool m = (nz >= 0.2f) && (nx >= -RELAXF) && (nx <= RELAXF)
                                  && (ny >= -RELAXF) && (ny <= RELAXF);

      const float sx = 0.5f * (nx + 1.0f) * PXW;
      const float sy = (1.0f - 0.5f * (ny + 1.0f)) * PXH;

      o_pos[3 * k + 0] = m ? sx : 0.0f;
      o_pos[3 * k + 1] = m ? sy : 0.0f;
      o_pos[3 * k + 2] = m ? nz : 0.0f;
      o_msk[k]         = m ? 1.0f : 0.0f;

      const float iz = 1.0f / z;
      const float a0 = iz * (V[0] - x * V[2]);
      const float a1 = iz * (V[4] - x * V[6]);
      const float a2 = iz * (V[8] - x * V[10]);
      const float b0 = iz * (V[1] - y * V[2]);
      const float b1 = iz * (V[5] - y * V[6]);
      const float b2 = iz * (V[9] - y * V[10]);

      const float* C = &cf[9 * k];
      const float u0 = C[0] * a0 + C[1] * a1 + C[2] * a2;
      const float u1 = C[3] * a0 + C[4] * a1 + C[5] * a2;
      const float u2 = C[6] * a0 + C[7] * a1 + C[8] * a2;
      const float v0 = C[0] * b0 + C[1] * b1 + C[2] * b2;
      const float v1 = C[3] * b0 + C[4] * b1 + C[5] * b2;
      const float v2 = C[6] * b0 + C[7] * b1 + C[8] * b2;

      o_cov[4 * k + 0] = m ? (a0 * u0 + a1 * u1 + a2 * u2) : 0.0f;
      o_cov[4 * k + 1] = m ? (a0 * v0 + a1 * v1 + a2 * v2) : 0.0f;
      o_cov[4 * k + 2] = m ? (b0 * u0 + b1 * u1 + b2 * u2) : 0.0f;
      o_cov[4 * k + 3] = m ? (b0 * v0 + b1 * v1 + b2 * v2) : 0.0f;
    }

    // ---- mask: naturally coalesced, direct store ----
    f4 tm = { o_msk[0], o_msk[1], o_msk[2], o_msk[3] };
    reinterpret_cast<f4*>(out + (size_t)7 * n)[(size_t)64 * wt + l] = tm;

    // ---- stage outputs in the same slice (WAR on LDS, lgkmcnt-ordered) ----
#pragma unroll
    for (int c = 0; c < 3; ++c) {
      f4 v = { o_pos[4 * c + 0], o_pos[4 * c + 1],
               o_pos[4 * c + 2], o_pos[4 * c + 3] };
      S[3 * l + c] = v;                       // stride-3 (odd): bank-optimal
    }
#pragma unroll
    for (int c = 0; c < 4; ++c) {
      f4 v = { o_cov[4 * c + 0], o_cov[4 * c + 1],
               o_cov[4 * c + 2], o_cov[4 * c + 3] };
      S[192 + 5 * l + c] = v;                 // stride-5 (odd, padded from 4)
    }

    // ---- coalesced stores ----
    f4* gop = reinterpret_cast<f4*>(out) + (size_t)192 * wt;
#pragma unroll
    for (int j = 0; j < 3; ++j) gop[l + 64 * j] = S[l + 64 * j];

    f4* goc = reinterpret_cast<f4*>(out + (size_t)3 * n) + (size_t)256 * wt;
#pragma unroll
    for (int j = 0; j < 4; ++j) {
      const int i = l + 64 * j;
      goc[i] = S[192 + 5 * (i >> 2) + (i & 3)];
    }

  } else if (wt == nwt) {
    // ---- tail: leftover 4-point groups (empty when n % 256 == 0) ----
    for (int g = nwt * 64 + l; g < (n >> 2); g += 64) {
      const float4* p4 = reinterpret_cast<const float4*>(pos3d) + (size_t)3 * g;
      const float4 ta = p4[0], tb = p4[1], tc = p4[2];
      float px[4], py[4], pz[4];
      px[0] = ta.x; py[0] = ta.y; pz[0] = ta.z;
      px[1] = ta.w; py[1] = tb.x; pz[1] = tb.y;
      px[2] = tb.z; py[2] = tb.w; pz[2] = tc.x;
      px[3] = tc.y; py[3] = tc.z; pz[3] = tc.w;

      const float4* c4 = reinterpret_cast<const float4*>(cov3d) + (size_t)9 * g;
      float cf[36];
#pragma unroll
      for (int i = 0; i < 9; ++i) {
        const float4 tt = c4[i];
        cf[4 * i + 0] = tt.x; cf[4 * i + 1] = tt.y;
        cf[4 * i + 2] = tt.z; cf[4 * i + 3] = tt.w;
      }

      float o_pos[12], o_cov[16], o_msk[4];
#pragma unroll
      for (int k = 0; k < 4; ++k) {
        const float x = px[k], y = py[k], z = pz[k];
        const float pm0 = V[0] * x + V[1] * y + V[2]  * z + V[3];
        const float pm1 = V[4] * x + V[5] * y + V[6]  * z + V[7];
        const float pm2 = V[8] * x + V[9] * y + V[10] * z + V[11];
        const float c0 = P[0]  * pm0 + P[1]  * pm1 + P[2]  * pm2 + P[3];
        const float c1 = P[4]  * pm0 + P[5]  * pm1 + P[6]  * pm2 + P[7];
        const float c2 = P[8]  * pm0 + P[9]  * pm1 + P[10] * pm2 + P[11];
        const float c3 = P[12] * pm0 + P[13] * pm1 + P[14] * pm2 + P[15];
        const float iw = 1.0f / (c3 + 1e-6f);
        const float nx = c0 * iw, ny = c1 * iw, nz = c2 * iw;
        const bool m = (nz >= 0.2f) && (nx >= -RELAXF) && (nx <= RELAXF)
                                    && (ny >= -RELAXF) && (ny <= RELAXF);
        const float sx = 0.5f * (nx + 1.0f) * PXW;
        const float sy = (1.0f - 0.5f * (ny + 1.0f)) * PXH;
        o_pos[3 * k + 0] = m ? sx : 0.0f;
        o_pos[3 * k + 1] = m ? sy : 0.0f;
        o_pos[3 * k + 2] = m ? nz : 0.0f;
        o_msk[k]         = m ? 1.0f : 0.0f;
        const float iz = 1.0f / z;
        const float a0 = iz * (V[0] - x * V[2]);
        const float a1 = iz * (V[4] - x * V[6]);
        const float a2 = iz * (V[8] - x * V[10]);
        const float b0 = iz * (V[1] - y * V[2]);
        const float b1 = iz * (V[5] - y * V[6]);
        const float b2 = iz * (V[9] - y * V[10]);
        const float* C = &cf[9 * k];
        const float u0 = C[0] * a0 + C[1] * a1 + C[2] * a2;
        const float u1 = C[3] * a0 + C[4] * a1 + C[5] * a2;
        const float u2 = C[6] * a0 + C[7] * a1 + C[8] * a2;
        const float v0 = C[0] * b0 + C[1] * b1 + C[2] * b2;
        const float v1 = C[3] * b0 + C[4] * b1 + C[5] * b2;
        const float v2 = C[6] * b0 + C[7] * b1 + C[8] * b2;
        o_cov[4 * k + 0] = m ? (a0 * u0 + a1 * u1 + a2 * u2) : 0.0f;
        o_cov[4 * k + 1] = m ? (a0 * v0 + a1 * v1 + a2 * v2) : 0.0f;
        o_cov[4 * k + 2] = m ? (b0 * u0 + b1 * u1 + b2 * u2) : 0.0f;
        o_cov[4 * k + 3] = m ? (b0 * v0 + b1 * v1 + b2 * v2) : 0.0f;
      }

      float4* op = reinterpret_cast<float4*>(out) + (size_t)3 * g;
      op[0] = make_float4(o_pos[0], o_pos[1], o_pos[2],  o_pos[3]);
      op[1] = make_float4(o_pos[4], o_pos[5], o_pos[6],  o_pos[7]);
      op[2] = make_float4(o_pos[8], o_pos[9], o_pos[10], o_pos[11]);
      float4* oc = reinterpret_cast<float4*>(out + (size_t)3 * n) + (size_t)4 * g;
#pragma unroll
      for (int k = 0; k < 4; ++k)
        oc[k] = make_float4(o_cov[4 * k + 0], o_cov[4 * k + 1],
                            o_cov[4 * k + 2], o_cov[4 * k + 3]);
      reinterpret_cast<float4*>(out + (size_t)7 * n)[g] =
          make_float4(o_msk[0], o_msk[1], o_msk[2], o_msk[3]);
    }
  }
}

extern "C" void kernel_launch(void* const* d_in, const int* in_sizes, int n_in,
                              void* d_out, int out_size, void* d_ws, size_t ws_size,
                              hipStream_t stream) {
  const float* pos3d = (const float*)d_in[0];
  const float* cov3d = (const float*)d_in[1];
  const float* view  = (const float*)d_in[2];
  const float* proj  = (const float*)d_in[3];

  const int n = in_sizes[0] / 3;            // 4,000,000

  const int groups = n >> 2;                             // 1,000,000
  const int blocks = (groups + 4 * 64 - 1) / (4 * 64);   // 3907
  cam_kernel<<<blocks, NT, 0, stream>>>(pos3d, cov3d, view, proj,
                                        (float*)d_out, n);
}